// Round 1
// baseline (724.530 us; speedup 1.0000x reference)
//
#include <hip/hip_runtime.h>

#define NBINS 256
#define CHANNELS 96              // B*C = 32*3
#define PIX_PER_CH (1024 * 1024) // H*W
#define CHUNKS 64                // blocks per channel
#define PIX_PER_BLOCK (PIX_PER_CH / CHUNKS) // 16384
#define THREADS 256
#define V4_PER_THREAD (PIX_PER_BLOCK / 4 / THREADS) // 16

// ---------------------------------------------------------------------------
// Pass 1: per-channel 256-bin histogram.
// 4 per-wave LDS sub-histograms to reduce LDS atomic contention; one global
// atomicAdd per (block, bin) at the end.
// ---------------------------------------------------------------------------
__global__ __launch_bounds__(THREADS) void hist_kernel(
    const float* __restrict__ in, int* __restrict__ hist) {
    __shared__ int sh[4][NBINS];
    const int t = threadIdx.x;
    const int wave = t >> 6;

    for (int i = t; i < 4 * NBINS; i += THREADS) ((int*)sh)[i] = 0;
    __syncthreads();

    const int c = blockIdx.x / CHUNKS;
    const int chunk = blockIdx.x % CHUNKS;
    const float4* in4 =
        (const float4*)(in + (size_t)c * PIX_PER_CH + (size_t)chunk * PIX_PER_BLOCK);

#pragma unroll
    for (int i = 0; i < V4_PER_THREAD; ++i) {
        float4 v = in4[i * THREADS + t];
        atomicAdd(&sh[wave][(int)v.x], 1);
        atomicAdd(&sh[wave][(int)v.y], 1);
        atomicAdd(&sh[wave][(int)v.z], 1);
        atomicAdd(&sh[wave][(int)v.w], 1);
    }
    __syncthreads();

    int sum = sh[0][t] + sh[1][t] + sh[2][t] + sh[3][t];
    if (sum) atomicAdd(&hist[c * NBINS + t], sum);
}

// ---------------------------------------------------------------------------
// Pass 2: build the 256-entry LUT per channel (96 blocks x 256 threads).
// Exact torchvision integer arithmetic; step==0 identity folded into LUT.
// ---------------------------------------------------------------------------
__global__ __launch_bounds__(THREADS) void lut_kernel(
    const int* __restrict__ hist, float* __restrict__ lut) {
    __shared__ int sh[NBINS];    // raw histogram
    __shared__ int scan[NBINS];  // inclusive cumsum (scratch during scan)
    __shared__ int red[NBINS];   // last-nonzero reduction
    const int t = threadIdx.x;
    const int c = blockIdx.x;

    const int h = hist[c * NBINS + t];
    sh[t] = h;
    int val = h;
    scan[t] = val;
    red[t] = (h != 0) ? t : -1;
    __syncthreads();

    // Hillis-Steele inclusive scan over 256 elements.
#pragma unroll
    for (int off = 1; off < NBINS; off <<= 1) {
        int add = (t >= off) ? scan[t - off] : 0;
        __syncthreads();
        val += add;
        scan[t] = val;
        __syncthreads();
    }

    // max-reduce for last nonzero bin index
#pragma unroll
    for (int off = NBINS / 2; off > 0; off >>= 1) {
        if (t < off) red[t] = max(red[t], red[t + off]);
        __syncthreads();
    }

    const int last_idx = red[0];             // total > 0 always => last_idx >= 0
    const int total = scan[NBINS - 1];
    const int last_val = sh[last_idx];
    const int step = (total - last_val) / (NBINS - 1);

    float out;
    if (step == 0) {
        out = (float)t;                      // identity: pixels are exact ints
    } else {
        int v = (t == 0) ? 0 : (scan[t - 1] + (step >> 1)) / step;
        out = (float)min(v, 255);
    }
    lut[c * NBINS + t] = out;
}

// ---------------------------------------------------------------------------
// Pass 3: remap via LDS-staged LUT, float4 in / float4 out.
// ---------------------------------------------------------------------------
__global__ __launch_bounds__(THREADS) void remap_kernel(
    const float* __restrict__ in, const float* __restrict__ lut,
    float* __restrict__ out) {
    __shared__ float slut[NBINS];
    const int t = threadIdx.x;
    const int c = blockIdx.x / CHUNKS;
    const int chunk = blockIdx.x % CHUNKS;

    slut[t] = lut[c * NBINS + t];
    __syncthreads();

    const size_t base = (size_t)c * PIX_PER_CH + (size_t)chunk * PIX_PER_BLOCK;
    const float4* in4 = (const float4*)(in + base);
    float4* out4 = (float4*)(out + base);

#pragma unroll
    for (int i = 0; i < V4_PER_THREAD; ++i) {
        float4 v = in4[i * THREADS + t];
        float4 r;
        r.x = slut[(int)v.x];
        r.y = slut[(int)v.y];
        r.z = slut[(int)v.z];
        r.w = slut[(int)v.w];
        out4[i * THREADS + t] = r;
    }
}

extern "C" void kernel_launch(void* const* d_in, const int* in_sizes, int n_in,
                              void* d_out, int out_size, void* d_ws, size_t ws_size,
                              hipStream_t stream) {
    const float* image = (const float*)d_in[0];
    float* out = (float*)d_out;

    // workspace layout: [0, 96*256*4)   int32 histograms
    //                   [96*256*4, ...) float32 LUTs
    int* hist = (int*)d_ws;
    float* lut = (float*)((char*)d_ws + CHANNELS * NBINS * sizeof(int));

    hipMemsetAsync(hist, 0, CHANNELS * NBINS * sizeof(int), stream);

    hist_kernel<<<CHANNELS * CHUNKS, THREADS, 0, stream>>>(image, hist);
    lut_kernel<<<CHANNELS, THREADS, 0, stream>>>(hist, lut);
    remap_kernel<<<CHANNELS * CHUNKS, THREADS, 0, stream>>>(image, lut, out);
}

// Round 3
// 645.428 us; speedup vs baseline: 1.1226x; 1.1226x over previous
//
#include <hip/hip_runtime.h>

#define NBINS 256
#define CHANNELS 96                         // B*C = 32*3
#define PIX_PER_CH (1024 * 1024)            // H*W
#define CHUNKS 64                           // blocks per channel
#define PIX_PER_BLOCK (PIX_PER_CH / CHUNKS) // 16384 pixels
#define THREADS 256
#define W_PER_BLOCK (PIX_PER_BLOCK / 4)     // 4096 packed words
#define W_PER_THREAD (W_PER_BLOCK / THREADS) // 16

typedef float float4v __attribute__((ext_vector_type(4)));

// ---------------------------------------------------------------------------
// Pass 1: histogram + byte-pack.
// NT float4 loads (read-once stream, keep L3 clean), per-wave LDS histograms,
// pack 4 pixels -> 1 uint into d_ws (100.7 MB, L3-resident for pass 3).
// ---------------------------------------------------------------------------
__global__ __launch_bounds__(THREADS) void hist_pack_kernel(
    const float* __restrict__ in, unsigned int* __restrict__ packed,
    int* __restrict__ hist) {
    __shared__ int sh[4][NBINS];
    const int t = threadIdx.x;
    const int wave = t >> 6;

    for (int i = t; i < 4 * NBINS; i += THREADS) ((int*)sh)[i] = 0;
    __syncthreads();

    const int c = blockIdx.x >> 6;       // / CHUNKS
    const int chunk = blockIdx.x & 63;   // % CHUNKS
    const size_t base4 =
        (size_t)c * (PIX_PER_CH / 4) + (size_t)chunk * W_PER_BLOCK;
    const float4v* in4 = (const float4v*)in + base4;
    unsigned int* w4 = packed + base4;

#pragma unroll
    for (int i = 0; i < W_PER_THREAD; ++i) {
        float4v v = __builtin_nontemporal_load(in4 + i * THREADS + t);
        unsigned b0 = (unsigned)v.x, b1 = (unsigned)v.y;
        unsigned b2 = (unsigned)v.z, b3 = (unsigned)v.w;
        atomicAdd(&sh[wave][b0], 1);
        atomicAdd(&sh[wave][b1], 1);
        atomicAdd(&sh[wave][b2], 1);
        atomicAdd(&sh[wave][b3], 1);
        w4[i * THREADS + t] = b0 | (b1 << 8) | (b2 << 16) | (b3 << 24);
    }
    __syncthreads();

    int sum = sh[0][t] + sh[1][t] + sh[2][t] + sh[3][t];
    if (sum) atomicAdd(&hist[c * NBINS + t], sum);
}

// ---------------------------------------------------------------------------
// Pass 2: LUT build — one wave (64 lanes) per channel, 4 bins/lane,
// pure shuffle scan, zero barriers.
// ---------------------------------------------------------------------------
__global__ __launch_bounds__(64) void lut_kernel(
    const int* __restrict__ hist, float* __restrict__ lut) {
    const int t = threadIdx.x;  // lane 0..63
    const int c = blockIdx.x;

    int4 h = ((const int4*)(hist + c * NBINS))[t];  // bins 4t .. 4t+3
    const int s0 = h.x, s1 = s0 + h.y, s2 = s1 + h.z, s3 = s2 + h.w;

    // wave-inclusive scan of per-lane totals
    int incl = s3;
#pragma unroll
    for (int off = 1; off < 64; off <<= 1) {
        int n = __shfl_up(incl, off);
        if (t >= off) incl += n;
    }
    const int excl = incl - s3;
    const int c0 = excl + s0, c1 = excl + s1, c2 = excl + s2, c3 = excl + s3;

    const int total = __shfl(incl, 63);

    // last nonzero bin: highest lane with any nonzero, then last-of-4 in it
    unsigned long long nz = __ballot(h.x | h.y | h.z | h.w);
    const int last_lane = 63 - __clzll(nz);  // total > 0 always
    const int lv = h.w ? h.w : (h.z ? h.z : (h.y ? h.y : h.x));
    const int last_val = __shfl(lv, last_lane);

    const int step = (total - last_val) / (NBINS - 1);

    float o0, o1, o2, o3;
    if (step == 0) {  // identity: pixels are exact integer floats
        o0 = (float)(4 * t);
        o1 = (float)(4 * t + 1);
        o2 = (float)(4 * t + 2);
        o3 = (float)(4 * t + 3);
    } else {
        const int half = step >> 1;
        int p = __shfl_up(c3, 1);
        int prev = t ? p : 0;  // cum[4t-1]
        o0 = (t == 0) ? 0.0f : (float)min((prev + half) / step, 255);
        o1 = (float)min((c0 + half) / step, 255);
        o2 = (float)min((c1 + half) / step, 255);
        o3 = (float)min((c2 + half) / step, 255);
    }
    float4v r = {o0, o1, o2, o3};
    ((float4v*)(lut + c * NBINS))[t] = r;
}

// ---------------------------------------------------------------------------
// Pass 3: remap from packed bytes (L3-resident), LDS LUT gather,
// NT float4 stores (write-once output, keep L3 for the byte array).
// ---------------------------------------------------------------------------
__global__ __launch_bounds__(THREADS) void remap_kernel(
    const unsigned int* __restrict__ packed, const float* __restrict__ lut,
    float* __restrict__ out) {
    __shared__ float slut[NBINS];
    const int t = threadIdx.x;
    const int c = blockIdx.x >> 6;
    const int chunk = blockIdx.x & 63;

    slut[t] = lut[c * NBINS + t];
    __syncthreads();

    const size_t base4 =
        (size_t)c * (PIX_PER_CH / 4) + (size_t)chunk * W_PER_BLOCK;
    const unsigned int* w4 = packed + base4;
    float4v* out4 = (float4v*)out + base4;

#pragma unroll
    for (int i = 0; i < W_PER_THREAD; ++i) {
        unsigned w = w4[i * THREADS + t];
        float4v r = {slut[w & 255], slut[(w >> 8) & 255], slut[(w >> 16) & 255],
                     slut[w >> 24]};
        __builtin_nontemporal_store(r, out4 + i * THREADS + t);
    }
}

extern "C" void kernel_launch(void* const* d_in, const int* in_sizes, int n_in,
                              void* d_out, int out_size, void* d_ws, size_t ws_size,
                              hipStream_t stream) {
    const float* image = (const float*)d_in[0];
    float* out = (float*)d_out;

    // workspace layout:
    //   [0, 100663296)            packed bytes (25,165,824 uints)
    //   [100663296, +96 KiB)      int32 histograms (96 x 256)
    //   [.., +96 KiB)             float32 LUTs (96 x 256)
    unsigned int* packed = (unsigned int*)d_ws;
    char* base = (char*)d_ws + (size_t)CHANNELS * PIX_PER_CH; // 100663296 B
    int* hist = (int*)base;
    float* lut = (float*)(base + CHANNELS * NBINS * sizeof(int));

    hipMemsetAsync(hist, 0, CHANNELS * NBINS * sizeof(int), stream);

    hist_pack_kernel<<<CHANNELS * CHUNKS, THREADS, 0, stream>>>(image, packed, hist);
    lut_kernel<<<CHANNELS, 64, 0, stream>>>(hist, lut);
    remap_kernel<<<CHANNELS * CHUNKS, THREADS, 0, stream>>>(packed, lut, out);
}